// Round 1
// 651.341 us; speedup vs baseline: 1.2749x; 1.2749x over previous
//
#include <hip/hip_runtime.h>

// RIMCell forward, MI355X. Round 4: pipelined MFMA GEMMs.
// - 2-deep register prefetch + double-buffered LDS, 1 barrier per 32-K step
// - kc/qc/vc fused into one 864-block launch
// - co GEMM split-K=2 (384 blocks) + fused reduce/mask epilogue
// f32 in/out; bf16 internal; weights converted f32->bf16 in the staging path.
// B=256, D=512, H=512, U=24, K=8, IK=64, IV=400, NIH=1, CK=CQ=32, NCH=4, CV=512.

typedef unsigned short u16;
typedef __bf16 bf16_t;
typedef bf16_t bf16x8 __attribute__((ext_vector_type(8)));
typedef float f32x16 __attribute__((ext_vector_type(16)));

union V8 { uint4 u; bf16x8 v; u16 us[8]; };

__device__ __forceinline__ float u2f(u16 u) {
    union { unsigned int i; float f; } c; c.i = ((unsigned int)u) << 16; return c.f;
}
// RNE f32->bf16 via HW convert (identical numerics to manual RNE bit-twiddle)
__device__ __forceinline__ u16 f2u(float f) {
    union { bf16_t b; u16 u; } c; c.b = (bf16_t)f; return c.u;
}

// ---------------- Stage 1: k0[b,64] = x[b]@key_w + key_b ; v0[b,400] = x[b]@value_w + value_b
__global__ __launch_bounds__(256) void kv_kernel(
    const float* __restrict__ x, const float* __restrict__ key_w, const float* __restrict__ key_b,
    const float* __restrict__ value_w, const float* __restrict__ value_b,
    float* __restrict__ k0, float* __restrict__ v0)
{
    __shared__ float xs[512];
    const int b = blockIdx.x, tid = threadIdx.x;
    for (int i = tid; i < 512; i += 256) xs[i] = x[b * 512 + i];
    __syncthreads();
    if (tid < 64) {
        float acc = 0.f;
        for (int d = 0; d < 512; ++d) acc += xs[d] * key_w[d * 64 + tid];
        k0[b * 64 + tid] = acc + key_b[tid];
    }
    for (int v = tid; v < 400; v += 256) {
        float acc = 0.f;
        for (int d = 0; d < 512; ++d) acc += xs[d] * value_w[d * 400 + v];
        v0[b * 400 + v] = acc + value_b[v];
    }
}

// ---------------- Stage 2: scores[b,u,0] = (hs[b,u]@query_w[u])·k0[b]/8 ; scores[b,u,1] = q·key_b/8
__global__ __launch_bounds__(64) void qscore_kernel(
    const float* __restrict__ hs, const float* __restrict__ query_w,
    const float* __restrict__ k0, const float* __restrict__ key_b,
    float* __restrict__ scores)
{
    __shared__ float hsu[512];
    const int u = blockIdx.x, b = blockIdx.y, lane = threadIdx.x;
    const float* h = hs + ((size_t)(b * 24 + u)) * 512;
    for (int i = lane; i < 512; i += 64) hsu[i] = h[i];
    __syncthreads();
    const float* qw = query_w + (size_t)u * 512 * 64 + lane;
    float q = 0.f;
    for (int d = 0; d < 512; ++d) q += hsu[d] * qw[(size_t)d * 64];
    float p0 = q * k0[b * 64 + lane];
    float p1 = q * key_b[lane];
    #pragma unroll
    for (int off = 32; off > 0; off >>= 1) {
        p0 += __shfl_down(p0, off);
        p1 += __shfl_down(p1, off);
    }
    if (lane == 0) {
        scores[(b * 24 + u) * 2 + 0] = p0 * 0.125f;
        scores[(b * 24 + u) * 2 + 1] = p1 * 0.125f;
    }
}

// ---------------- Stage 3: stable top-8 mask; probs = softmax over t(2)
__global__ __launch_bounds__(64) void topk_kernel(
    const float* __restrict__ scores, float* __restrict__ mask, float* __restrict__ probs)
{
    __shared__ float s0[24];
    const int b = blockIdx.x, tid = threadIdx.x;
    if (tid < 24) s0[tid] = scores[(b * 24 + tid) * 2];
    __syncthreads();
    if (tid < 24) {
        const float su = s0[tid];
        int rank = 0;
        for (int t = 0; t < 24; ++t) {
            float st = s0[t];
            rank += (st > su) || (st == su && t < tid);
        }
        mask[b * 24 + tid] = (rank < 8) ? 1.f : 0.f;
        const float a = su, c = scores[(b * 24 + tid) * 2 + 1];
        const float m = fmaxf(a, c);
        const float e0 = expf(a - m), e1 = expf(c - m);
        const float inv = 1.f / (e0 + e1);
        probs[(b * 24 + tid) * 2 + 0] = e0 * inv;
        probs[(b * 24 + tid) * 2 + 1] = e1 * inv;
    }
}

// ---------------- Stage 4: inp[b,u,v] (stride 416, zero-padded cols 400..415), bf16
__global__ __launch_bounds__(256) void inp_kernel(
    const float* __restrict__ probs, const float* __restrict__ v0,
    const float* __restrict__ value_b, const float* __restrict__ mask,
    u16* __restrict__ inp)
{
    const int idx = blockIdx.x * 256 + threadIdx.x;  // exactly B*U*416
    const int v = idx % 416, bu = idx / 416, b = bu / 24;
    float val = 0.f;
    if (v < 400)
        val = (probs[bu * 2] * v0[b * 400 + v] + probs[bu * 2 + 1] * value_b[v]) * mask[bu];
    inp[idx] = f2u(val);
}

// ---------------- f32 -> bf16 convert (hs -> hsb)
__global__ __launch_bounds__(256) void tobf16_kernel(
    const float* __restrict__ src, u16* __restrict__ dst)
{
    const int idx = blockIdx.x * 256 + threadIdx.x;
    dst[idx] = f2u(src[idx]);
}

// ================= Pipelined GEMM core =================
// 128(M)x128(N) tile, BK=32, 4 waves each 64x64 via 2x2 mfma_32x32x16_bf16.
// Double-buffered LDS + 2-step-deep register prefetch; ONE barrier per K-step.
// aB*: pre-offset to (m0+ar)*lda + ac.  bB*: pre-offset to u*bus + bkg*ldb + n0 + bn.
__device__ __forceinline__ void gemm_pipe(
    const u16* __restrict__ aB1, int lda1,
    const float* __restrict__ bB1, int ldb1, int K1, int ns1,
    const u16* __restrict__ aB2, int lda2,
    const float* __restrict__ bB2, int ldb2, int K2, int ns2,
    int ar, int ac, int bn, int bkg, int wm, int wn, int fr, int kh,
    u16* __restrict__ As0, u16* __restrict__ As1,
    u16* __restrict__ Bs0, u16* __restrict__ Bs1,
    f32x16 acc[2][2])
{
    const int nst = ns1 + ns2;
    uint4 a0A, a1A, a0B, a1B;
    float rbA[16], rbB[16];

    auto issue = [&](int t, uint4& x0, uint4& x1, float* rb) {
        const bool s2 = (t >= ns1);
        const int k0 = (s2 ? t - ns1 : t) << 5;
        const int lda = s2 ? lda2 : lda1;
        const int ldb = s2 ? ldb2 : ldb1;
        const int K   = s2 ? K2 : K1;
        const u16* ap = (s2 ? aB2 : aB1) + k0;
        x0 = *(const uint4*)ap;
        x1 = *(const uint4*)(ap + (size_t)64 * lda);
        const float* bp = (s2 ? bB2 : bB1) + (size_t)k0 * ldb;
        if (k0 + 32 <= K) {
            #pragma unroll
            for (int j = 0; j < 16; ++j) rb[j] = bp[(size_t)j * ldb];
        } else {
            #pragma unroll
            for (int j = 0; j < 16; ++j)
                rb[j] = (k0 + bkg + j < K) ? bp[(size_t)j * ldb] : 0.f;
        }
    };

    auto convstore = [&](const uint4& x0, const uint4& x1, const float* rb,
                         u16* __restrict__ As, u16* __restrict__ Bs) {
        *(uint4*)&As[ar * 40 + ac]        = x0;
        *(uint4*)&As[(ar + 64) * 40 + ac] = x1;
        V8 lo, hi;
        #pragma unroll
        for (int j = 0; j < 8; ++j) lo.us[j] = f2u(rb[j]);
        #pragma unroll
        for (int j = 0; j < 8; ++j) hi.us[j] = f2u(rb[8 + j]);
        *(uint4*)&Bs[bn * 40 + bkg]     = lo.u;
        *(uint4*)&Bs[bn * 40 + bkg + 8] = hi.u;
    };

    auto compute = [&](const u16* __restrict__ As, const u16* __restrict__ Bs) {
        #pragma unroll
        for (int kk = 0; kk < 32; kk += 16) {
            V8 a0, a1, b0, b1;
            a0.u = *(const uint4*)&As[(wm + fr) * 40 + kk + kh];
            a1.u = *(const uint4*)&As[(wm + 32 + fr) * 40 + kk + kh];
            b0.u = *(const uint4*)&Bs[(wn + fr) * 40 + kk + kh];
            b1.u = *(const uint4*)&Bs[(wn + 32 + fr) * 40 + kk + kh];
            acc[0][0] = __builtin_amdgcn_mfma_f32_32x32x16_bf16(a0.v, b0.v, acc[0][0], 0, 0, 0);
            acc[0][1] = __builtin_amdgcn_mfma_f32_32x32x16_bf16(a0.v, b1.v, acc[0][1], 0, 0, 0);
            acc[1][0] = __builtin_amdgcn_mfma_f32_32x32x16_bf16(a1.v, b0.v, acc[1][0], 0, 0, 0);
            acc[1][1] = __builtin_amdgcn_mfma_f32_32x32x16_bf16(a1.v, b1.v, acc[1][1], 0, 0, 0);
        }
    };

    // prologue: stage step 0, prefetch step 1
    issue(0, a0A, a1A, rbA);
    convstore(a0A, a1A, rbA, As0, Bs0);
    if (nst > 1) issue(1, a0B, a1B, rbB);
    __syncthreads();

    for (int t = 0; t < nst; t += 2) {
        compute(As0, Bs0);
        if (t + 1 < nst) convstore(a0B, a1B, rbB, As1, Bs1);
        if (t + 2 < nst) issue(t + 2, a0A, a1A, rbA);
        __syncthreads();
        if (t + 1 < nst) {
            compute(As1, Bs1);
            if (t + 2 < nst) convstore(a0A, a1A, rbA, As0, Bs0);
            if (t + 3 < nst) issue(t + 3, a0B, a1B, rbB);
            __syncthreads();
        }
    }
}

// ---------------- general batched-per-u GEMM: C[u] = A1[u]@B1[u] (+ A2[u]@B2[u])
// mode 0: f32 store (+ split-K partial offset). mode 1: bf16 store.
// blockIdx.y: bit0 = m-block, >>1 = split-K slice (skA/skB/skC = per-slice elem offsets).
__global__ __launch_bounds__(256, 2) void mfma_gemm(
    const u16* __restrict__ A1, int lda1, int aus1,
    const float* __restrict__ B1, int ldb1, int bus1, int K1,
    const u16* __restrict__ A2, int lda2, int aus2,
    const float* __restrict__ B2, int ldb2, int bus2, int K2,
    void* __restrict__ Cv, int ldc, int cus, int mode,
    int skA, int skB, int skC)
{
    __shared__ __align__(16) u16 As[2][128 * 40];  // rows padded 32->40: 2-way-only bank aliasing
    __shared__ __align__(16) u16 Bs[2][128 * 40];  // n-major, k-contiguous
    const int u = blockIdx.z;
    const int n0 = blockIdx.x * 128;
    const int mb = blockIdx.y & 1, sk = blockIdx.y >> 1;
    const int m0 = mb * 128;
    const int tid = threadIdx.x;
    const int ar = tid >> 2, ac = (tid & 3) * 8;
    const int bn = tid & 127, bkg = (tid >> 7) * 16;
    const int w = tid >> 6, lane = tid & 63;
    const int wm = (w >> 1) * 64, wn = (w & 1) * 64;
    const int fr = lane & 31, kh = (lane >> 5) * 8;

    const int ns1 = (K1 + 31) >> 5;
    const int ns2 = K2 ? (K2 + 31) >> 5 : 0;

    const u16* aB1 = A1 + (size_t)sk * skA + (size_t)u * aus1 + (size_t)(m0 + ar) * lda1 + ac;
    const float* bB1 = B1 + (size_t)sk * skB + (size_t)u * bus1 + (size_t)bkg * ldb1 + n0 + bn;
    const u16* aB2 = aB1; const float* bB2 = bB1; int lda2e = lda1, ldb2e = ldb1;
    if (K2) {
        aB2 = A2 + (size_t)u * aus2 + (size_t)(m0 + ar) * lda2 + ac;
        bB2 = B2 + (size_t)u * bus2 + (size_t)bkg * ldb2 + n0 + bn;
        lda2e = lda2; ldb2e = ldb2;
    }

    f32x16 acc[2][2];
    #pragma unroll
    for (int i = 0; i < 2; ++i)
        #pragma unroll
        for (int j = 0; j < 2; ++j)
            #pragma unroll
            for (int r = 0; r < 16; ++r) acc[i][j][r] = 0.f;

    gemm_pipe(aB1, lda1, bB1, ldb1, K1, ns1,
              aB2, lda2e, bB2, ldb2e, K2, ns2,
              ar, ac, bn, bkg, wm, wn, fr, kh,
              As[0], As[1], Bs[0], Bs[1], acc);

    // epilogue. C/D map (verified m74/m101): col=lane&31, row=(reg&3)+8*(reg>>2)+4*(lane>>5)
    const size_t skoff = (size_t)sk * (size_t)skC;
    const int rbase = (lane >> 5) * 4;
    #pragma unroll
    for (int i = 0; i < 2; ++i) {
        #pragma unroll
        for (int j = 0; j < 2; ++j) {
            const int gn = n0 + wn + j * 32 + fr;
            #pragma unroll
            for (int r = 0; r < 16; ++r) {
                const int row = (r & 3) + 8 * (r >> 2) + rbase;
                const int gm = m0 + wm + i * 32 + row;
                const size_t idx = (size_t)u * cus + (size_t)gm * ldc + gn + skoff;
                if (mode == 0) ((float*)Cv)[idx] = acc[i][j][r];
                else           ((u16*)Cv)[idx]  = f2u(acc[i][j][r]);
            }
        }
    }
}

// ---------------- fused kc/qc/vc GEMM: A = ht (M=256,K=512); bx selects weight/output
__global__ __launch_bounds__(256, 2) void mfma_gemm_kqv(
    const u16* __restrict__ ht,
    const float* __restrict__ kc_w, const float* __restrict__ qc_w, const float* __restrict__ vc_w,
    u16* __restrict__ kc, u16* __restrict__ qcb, u16* __restrict__ vc)
{
    __shared__ __align__(16) u16 As[2][128 * 40];
    __shared__ __align__(16) u16 Bs[2][128 * 40];
    const int u = blockIdx.z;
    const int bx = blockIdx.x;
    const int m0 = blockIdx.y * 128;
    const int tid = threadIdx.x;
    const int ar = tid >> 2, ac = (tid & 3) * 8;
    const int bn = tid & 127, bkg = (tid >> 7) * 16;
    const int w = tid >> 6, lane = tid & 63;
    const int wm = (w >> 1) * 64, wn = (w & 1) * 64;
    const int fr = lane & 31, kh = (lane >> 5) * 8;

    const float* Bw; u16* Cd; int ldb, bus, n0, ldc, cus;
    if (bx == 0)      { Bw = kc_w; Cd = kc;  ldb = 128;  bus = 512 * 128;  n0 = 0;              ldc = 3072;  cus = 128;  }
    else if (bx == 1) { Bw = qc_w; Cd = qcb; ldb = 128;  bus = 512 * 128;  n0 = 0;              ldc = 3072;  cus = 128;  }
    else              { Bw = vc_w; Cd = vc;  ldb = 2048; bus = 512 * 2048; n0 = (bx - 2) * 128; ldc = 49152; cus = 2048; }

    const u16* aB = ht + (size_t)u * 512 + (size_t)(m0 + ar) * 12288 + ac;
    const float* bB = Bw + (size_t)u * bus + (size_t)bkg * ldb + n0 + bn;

    f32x16 acc[2][2];
    #pragma unroll
    for (int i = 0; i < 2; ++i)
        #pragma unroll
        for (int j = 0; j < 2; ++j)
            #pragma unroll
            for (int r = 0; r < 16; ++r) acc[i][j][r] = 0.f;

    gemm_pipe(aB, 12288, bB, ldb, 512, 16,
              aB, 12288, bB, ldb, 0, 0,
              ar, ac, bn, bkg, wm, wn, fr, kh,
              As[0], As[1], Bs[0], Bs[1], acc);

    const int rbase = (lane >> 5) * 4;
    #pragma unroll
    for (int i = 0; i < 2; ++i) {
        #pragma unroll
        for (int j = 0; j < 2; ++j) {
            const int gn = n0 + wn + j * 32 + fr;
            #pragma unroll
            for (int r = 0; r < 16; ++r) {
                const int row = (r & 3) + 8 * (r >> 2) + rbase;
                const int gm = m0 + wm + i * 32 + row;
                Cd[(size_t)u * cus + (size_t)gm * ldc + gn] = f2u(acc[i][j][r]);
            }
        }
    }
}

// ---------------- Stage 6: LSTM gates; writes h_t (ws, bf16) and cs_new (d_out, f32 select)
__global__ __launch_bounds__(256) void gates_kernel(
    const float* __restrict__ preact, const float* __restrict__ cs,
    const float* __restrict__ mask,
    u16* __restrict__ ht, float* __restrict__ out_cs)
{
    const int idx = blockIdx.x * 256 + threadIdx.x;  // exactly B*U*512
    const int h = idx & 511, bu = idx >> 9;
    const float* pre = preact + (size_t)bu * 2048;
    const float it = 1.f / (1.f + expf(-pre[h]));
    const float ft = 1.f / (1.f + expf(-pre[512 + h]));
    const float ot = 1.f / (1.f + expf(-pre[1024 + h]));
    const float gt = tanhf(pre[1536 + h]);
    const float c = cs[idx] * ft + it * gt;
    ht[idx] = f2u(ot * tanhf(c));
    out_cs[idx] = (mask[bu] != 0.f) ? c : cs[idx];  // passthrough bit-exact when unmasked
}

// ---------------- Stage 10: per (u, head, b) attention over t=24; skip unmasked u
__global__ __launch_bounds__(64) void attn_kernel(
    const u16* __restrict__ qc, const u16* __restrict__ kc, const u16* __restrict__ vc,
    const float* __restrict__ mask, u16* __restrict__ ctx)
{
    const int u = blockIdx.x, nc = blockIdx.y, b = blockIdx.z;
    if (mask[b * 24 + u] == 0.f) return;  // ctx rows discarded by co epilogue
    const int lane = threadIdx.x;
    __shared__ float kcs[24][32];
    __shared__ float qv[32];
    __shared__ float ss[24];
    __shared__ float ps[24];
    for (int i = lane; i < 24 * 32; i += 64) {
        const int t = i >> 5, k = i & 31;
        kcs[t][k] = u2f(kc[((size_t)(b * 24 + t)) * 128 + nc * 32 + k]);
    }
    if (lane < 32) qv[lane] = u2f(qc[((size_t)(b * 24 + u)) * 128 + nc * 32 + lane]);
    __syncthreads();
    if (lane < 24) {
        float s = 0.f;
        for (int k = 0; k < 32; ++k) s += qv[k] * kcs[lane][k];
        ss[lane] = s * 0.17677669529663687f;  // 1/sqrt(32)
    }
    __syncthreads();
    float m = -1e30f;
    for (int t = 0; t < 24; ++t) m = fmaxf(m, ss[t]);
    float sum = 0.f;
    for (int t = 0; t < 24; ++t) sum += expf(ss[t] - m);
    const float inv = 1.f / sum;
    if (lane < 24) ps[lane] = expf(ss[lane] - m) * inv;
    __syncthreads();
    float acc[8] = {};
    const u16* vcb = vc + (size_t)b * 24 * 2048 + nc * 512 + lane;
    for (int t = 0; t < 24; ++t) {
        const float pt = ps[t];
        const u16* vr = vcb + (size_t)t * 2048;
        #pragma unroll
        for (int j = 0; j < 8; ++j) acc[j] += pt * u2f(vr[j * 64]);
    }
    u16* cb = ctx + ((size_t)(b * 24 + u)) * 2048 + nc * 512 + lane;
    #pragma unroll
    for (int j = 0; j < 8; ++j) cb[j * 64] = f2u(acc[j]);
}

// ---------------- co split-K reduce + epilogue: hs_new = mask ? p0+p1+h_t : hs
__global__ __launch_bounds__(256) void co_reduce(
    const float* __restrict__ p, const float* __restrict__ mask,
    const u16* __restrict__ ht, const float* __restrict__ hs,
    float* __restrict__ out_hs)
{
    const int idx = blockIdx.x * 256 + threadIdx.x;  // exactly B*U*512
    const int bu = idx >> 9;
    out_hs[idx] = (mask[bu] != 0.f)
        ? (p[idx] + p[idx + 6144 * 512] + u2f(ht[idx]))
        : hs[idx];
}

extern "C" void kernel_launch(void* const* d_in, const int* in_sizes, int n_in,
                              void* d_out, int out_size, void* d_ws, size_t ws_size,
                              hipStream_t stream)
{
    (void)in_sizes; (void)n_in; (void)out_size; (void)ws_size;
    const float* x       = (const float*)d_in[0];
    const float* hs      = (const float*)d_in[1];
    const float* cs      = (const float*)d_in[2];
    const float* key_w   = (const float*)d_in[3];
    const float* key_b   = (const float*)d_in[4];
    const float* value_w = (const float*)d_in[5];
    const float* value_b = (const float*)d_in[6];
    const float* query_w = (const float*)d_in[7];
    const float* i2h_w   = (const float*)d_in[8];
    const float* h2h_w   = (const float*)d_in[9];
    const float* qc_w    = (const float*)d_in[10];
    const float* kc_w    = (const float*)d_in[11];
    const float* vc_w    = (const float*)d_in[12];
    const float* co_w    = (const float*)d_in[13];

    // ws layout (bytes); vc/ctx alias the dead preact region; co partials alias dead vc
    char* ws = (char*)d_ws;
    float* k0     = (float*)(ws + 0);          // 256*64*4    = 65536
    float* v0     = (float*)(ws + 65536);      // 256*400*4   = 409600
    float* scores = (float*)(ws + 475136);     // 256*24*2*4  = 49152
    float* probs  = (float*)(ws + 524288);     // 49152
    float* mask   = (float*)(ws + 573440);     // 256*24*4    = 24576
    u16*   inp    = (u16*)  (ws + 598016);     // 256*24*416*2 = 5111808 (K padded to 416)
    float* preact = (float*)(ws + 5709824);    // 256*24*2048*4 = 50331648
    u16*   vc     = (u16*)  (ws + 5709824);    // alias (preact dead after gates)
    float* co_p   = (float*)(ws + 5709824);    // alias (vc dead after attn); 2*6144*512*4 = 25165824
    u16*   ctx    = (u16*)  (ws + 30875648);   // alias, second half of preact region
    u16*   ht     = (u16*)  (ws + 56041472);   // 256*24*512*2 = 6291456
    u16*   kc     = (u16*)  (ws + 62332928);   // 256*24*128*2 = 1572864
    u16*   qcb    = (u16*)  (ws + 63905792);   // 1572864
    u16*   hsb    = (u16*)  (ws + 65478656);   // 6291456 (total ~71.8MB)

    float* out_hs = (float*)d_out;
    float* out_cs = out_hs + (size_t)256 * 24 * 512;

    kv_kernel<<<256, 256, 0, stream>>>(x, key_w, key_b, value_w, value_b, k0, v0);
    qscore_kernel<<<dim3(24, 256), 64, 0, stream>>>(hs, query_w, k0, key_b, scores);
    topk_kernel<<<256, 64, 0, stream>>>(scores, mask, probs);
    inp_kernel<<<(256 * 24 * 416) / 256, 256, 0, stream>>>(probs, v0, value_b, mask, inp);
    tobf16_kernel<<<(256 * 24 * 512) / 256, 256, 0, stream>>>(hs, hsb);

    // preact = inp@i2h_w[u] + hs@h2h_w[u]   (M=256, N=2048, K=400+512)
    mfma_gemm<<<dim3(16, 2, 24), 256, 0, stream>>>(
        inp, 9984, 416, i2h_w, 2048, 400 * 2048, 400,
        hsb, 12288, 512, h2h_w, 2048, 512 * 2048, 512,
        preact, 49152, 2048, 0, 0, 0, 0);

    gates_kernel<<<12288, 256, 0, stream>>>(preact, cs, mask, ht, out_cs);

    // kc/qc/vc fused: M=256, K=512; N = 128 + 128 + 2048 (18 n-blocks)
    mfma_gemm_kqv<<<dim3(18, 2, 24), 256, 0, stream>>>(ht, kc_w, qc_w, vc_w, kc, qcb, vc);

    attn_kernel<<<dim3(24, 4, 256), 64, 0, stream>>>(qcb, kc, vc, mask, ctx);

    // co partials: M=256, N=512, K=2048 split into 2x1024 (grid.y = 2 m-blocks x 2 k-slices)
    mfma_gemm<<<dim3(4, 4, 24), 256, 0, stream>>>(
        ctx, 49152, 2048, co_w, 512, 2048 * 512, 1024,
        nullptr, 0, 0, nullptr, 0, 0, 0,
        co_p, 12288, 512, 0, 1024, 1024 * 512, 6144 * 512);

    co_reduce<<<12288, 256, 0, stream>>>(co_p, mask, ht, hs, out_hs);
}

// Round 3
// 594.797 us; speedup vs baseline: 1.3961x; 1.0951x over previous
//
#include <hip/hip_runtime.h>

// RIMCell forward, MI355X. Round 6: resubmit of Round 5 (infra failure, no counters).
// - gemm_pipe barriers = inline-asm "s_waitcnt lgkmcnt(0); s_barrier":
//   register-prefetch loads stay in flight across the barrier (T4-lite).
// - issue() hoisted to right after its register set is freed (~2.5-phase cover).
// - tobf16 fused into qscore; kv_kernel 512 threads; attn 256-thread blocks.
// f32 in/out; bf16 internal; weights converted f32->bf16 in the staging path.
// B=256, D=512, H=512, U=24, K=8, IK=64, IV=400, NIH=1, CK=CQ=32, NCH=4, CV=512.

typedef unsigned short u16;
typedef __bf16 bf16_t;
typedef bf16_t bf16x8 __attribute__((ext_vector_type(8)));
typedef float f32x16 __attribute__((ext_vector_type(16)));

union V8 { uint4 u; bf16x8 v; u16 us[8]; };

__device__ __forceinline__ float u2f(u16 u) {
    union { unsigned int i; float f; } c; c.i = ((unsigned int)u) << 16; return c.f;
}
// RNE f32->bf16 via HW convert
__device__ __forceinline__ u16 f2u(float f) {
    union { bf16_t b; u16 u; } c; c.b = (bf16_t)f; return c.u;
}

// LDS-visibility barrier that does NOT drain vmcnt: global register-prefetch
// loads stay in flight across it. Single asm => compiler cannot insert its
// own vmcnt(0), and the "memory" clobber pins all LDS ops on either side.
__device__ __forceinline__ void bar_lds() {
    asm volatile("s_waitcnt lgkmcnt(0)\n\ts_barrier" ::: "memory");
}

// ---------------- Stage 1: k0[b,64] = x[b]@key_w + key_b ; v0[b,400] = x[b]@value_w + value_b
__global__ __launch_bounds__(512) void kv_kernel(
    const float* __restrict__ x, const float* __restrict__ key_w, const float* __restrict__ key_b,
    const float* __restrict__ value_w, const float* __restrict__ value_b,
    float* __restrict__ k0, float* __restrict__ v0)
{
    __shared__ float xs[512];
    const int b = blockIdx.x, tid = threadIdx.x;
    xs[tid] = x[b * 512 + tid];
    __syncthreads();
    if (tid < 64) {
        float acc = 0.f;
        for (int d = 0; d < 512; ++d) acc += xs[d] * key_w[d * 64 + tid];
        k0[b * 64 + tid] = acc + key_b[tid];
    } else if (tid < 464) {
        const int v = tid - 64;
        float acc = 0.f;
        for (int d = 0; d < 512; ++d) acc += xs[d] * value_w[d * 400 + v];
        v0[b * 400 + v] = acc + value_b[v];
    }
}

// ---------------- Stage 2: scores + fused hs->bf16 convert
__global__ __launch_bounds__(64) void qscore_kernel(
    const float* __restrict__ hs, const float* __restrict__ query_w,
    const float* __restrict__ k0, const float* __restrict__ key_b,
    float* __restrict__ scores, u16* __restrict__ hsb)
{
    __shared__ float hsu[512];
    const int u = blockIdx.x, b = blockIdx.y, lane = threadIdx.x;
    const size_t base = ((size_t)(b * 24 + u)) * 512;
    const float* h = hs + base;
    for (int i = lane; i < 512; i += 64) {
        const float v = h[i];
        hsu[i] = v;
        hsb[base + i] = f2u(v);
    }
    __syncthreads();
    const float* qw = query_w + (size_t)u * 512 * 64 + lane;
    float q = 0.f;
    for (int d = 0; d < 512; ++d) q += hsu[d] * qw[(size_t)d * 64];
    float p0 = q * k0[b * 64 + lane];
    float p1 = q * key_b[lane];
    #pragma unroll
    for (int off = 32; off > 0; off >>= 1) {
        p0 += __shfl_down(p0, off);
        p1 += __shfl_down(p1, off);
    }
    if (lane == 0) {
        scores[(b * 24 + u) * 2 + 0] = p0 * 0.125f;
        scores[(b * 24 + u) * 2 + 1] = p1 * 0.125f;
    }
}

// ---------------- Stage 3: stable top-8 mask; probs = softmax over t(2)
__global__ __launch_bounds__(64) void topk_kernel(
    const float* __restrict__ scores, float* __restrict__ mask, float* __restrict__ probs)
{
    __shared__ float s0[24];
    const int b = blockIdx.x, tid = threadIdx.x;
    if (tid < 24) s0[tid] = scores[(b * 24 + tid) * 2];
    __syncthreads();
    if (tid < 24) {
        const float su = s0[tid];
        int rank = 0;
        for (int t = 0; t < 24; ++t) {
            float st = s0[t];
            rank += (st > su) || (st == su && t < tid);
        }
        mask[b * 24 + tid] = (rank < 8) ? 1.f : 0.f;
        const float a = su, c = scores[(b * 24 + tid) * 2 + 1];
        const float m = fmaxf(a, c);
        const float e0 = expf(a - m), e1 = expf(c - m);
        const float inv = 1.f / (e0 + e1);
        probs[(b * 24 + tid) * 2 + 0] = e0 * inv;
        probs[(b * 24 + tid) * 2 + 1] = e1 * inv;
    }
}

// ---------------- Stage 4: inp[b,u,v] (stride 416, zero-padded cols 400..415), bf16
__global__ __launch_bounds__(256) void inp_kernel(
    const float* __restrict__ probs, const float* __restrict__ v0,
    const float* __restrict__ value_b, const float* __restrict__ mask,
    u16* __restrict__ inp)
{
    const int idx = blockIdx.x * 256 + threadIdx.x;  // exactly B*U*416
    const int v = idx % 416, bu = idx / 416, b = bu / 24;
    float val = 0.f;
    if (v < 400)
        val = (probs[bu * 2] * v0[b * 400 + v] + probs[bu * 2 + 1] * value_b[v]) * mask[bu];
    inp[idx] = f2u(val);
}

// ================= Pipelined GEMM core =================
// 128(M)x128(N) tile, BK=32, 4 waves each 64x64 via 2x2 mfma_32x32x16_bf16.
// Double-buffered LDS + 2-set register prefetch; bar_lds() keeps global
// loads in flight across barriers (~2.5 phases of latency cover).
__device__ __forceinline__ void gemm_pipe(
    const u16* __restrict__ aB1, int lda1,
    const float* __restrict__ bB1, int ldb1, int K1, int ns1,
    const u16* __restrict__ aB2, int lda2,
    const float* __restrict__ bB2, int ldb2, int K2, int ns2,
    int ar, int ac, int bn, int bkg, int wm, int wn, int fr, int kh,
    u16* __restrict__ As0, u16* __restrict__ As1,
    u16* __restrict__ Bs0, u16* __restrict__ Bs1,
    f32x16 acc[2][2])
{
    const int nst = ns1 + ns2;
    uint4 a0A, a1A, a0B, a1B;
    float rbA[16], rbB[16];

    auto issue = [&](int t, uint4& x0, uint4& x1, float* rb) {
        const bool s2 = (t >= ns1);
        const int k0 = (s2 ? t - ns1 : t) << 5;
        const int lda = s2 ? lda2 : lda1;
        const int ldb = s2 ? ldb2 : ldb1;
        const int K   = s2 ? K2 : K1;
        const u16* ap = (s2 ? aB2 : aB1) + k0;
        x0 = *(const uint4*)ap;
        x1 = *(const uint4*)(ap + (size_t)64 * lda);
        const float* bp = (s2 ? bB2 : bB1) + (size_t)k0 * ldb;
        if (k0 + 32 <= K) {
            #pragma unroll
            for (int j = 0; j < 16; ++j) rb[j] = bp[(size_t)j * ldb];
        } else {
            #pragma unroll
            for (int j = 0; j < 16; ++j)
                rb[j] = (k0 + bkg + j < K) ? bp[(size_t)j * ldb] : 0.f;
        }
    };

    auto convstore = [&](const uint4& x0, const uint4& x1, const float* rb,
                         u16* __restrict__ As, u16* __restrict__ Bs) {
        *(uint4*)&As[ar * 40 + ac]        = x0;
        *(uint4*)&As[(ar + 64) * 40 + ac] = x1;
        V8 lo, hi;
        #pragma unroll
        for (int j = 0; j < 8; ++j) lo.us[j] = f2u(rb[j]);
        #pragma unroll
        for (int j = 0; j < 8; ++j) hi.us[j] = f2u(rb[8 + j]);
        *(uint4*)&Bs[bn * 40 + bkg]     = lo.u;
        *(uint4*)&Bs[bn * 40 + bkg + 8] = hi.u;
    };

    auto compute = [&](const u16* __restrict__ As, const u16* __restrict__ Bs) {
        #pragma unroll
        for (int kk = 0; kk < 32; kk += 16) {
            V8 a0, a1, b0, b1;
            a0.u = *(const uint4*)&As[(wm + fr) * 40 + kk + kh];
            a1.u = *(const uint4*)&As[(wm + 32 + fr) * 40 + kk + kh];
            b0.u = *(const uint4*)&Bs[(wn + fr) * 40 + kk + kh];
            b1.u = *(const uint4*)&Bs[(wn + 32 + fr) * 40 + kk + kh];
            acc[0][0] = __builtin_amdgcn_mfma_f32_32x32x16_bf16(a0.v, b0.v, acc[0][0], 0, 0, 0);
            acc[0][1] = __builtin_amdgcn_mfma_f32_32x32x16_bf16(a0.v, b1.v, acc[0][1], 0, 0, 0);
            acc[1][0] = __builtin_amdgcn_mfma_f32_32x32x16_bf16(a1.v, b0.v, acc[1][0], 0, 0, 0);
            acc[1][1] = __builtin_amdgcn_mfma_f32_32x32x16_bf16(a1.v, b1.v, acc[1][1], 0, 0, 0);
        }
    };

    // prologue: steps 0,1 in flight; stage 0; refill set A with step 2
    issue(0, a0A, a1A, rbA);
    if (nst > 1) issue(1, a0B, a1B, rbB);
    convstore(a0A, a1A, rbA, As0, Bs0);
    if (nst > 2) issue(2, a0A, a1A, rbA);
    bar_lds();

    int t = 0;
    for (; t + 2 <= nst; t += 2) {
        compute(As0, Bs0);                          // step t
        convstore(a0B, a1B, rbB, As1, Bs1);         // step t+1 -> L1
        if (t + 3 < nst) issue(t + 3, a0B, a1B, rbB);
        bar_lds();
        compute(As1, Bs1);                          // step t+1
        if (t + 2 < nst) convstore(a0A, a1A, rbA, As0, Bs0);  // step t+2 -> L0
        if (t + 4 < nst) issue(t + 4, a0A, a1A, rbA);
        bar_lds();
    }
    if (t < nst) compute(As0, Bs0);                 // odd tail step
}

// ---------------- general batched-per-u GEMM: C[u] = A1[u]@B1[u] (+ A2[u]@B2[u])
// mode 0: f32 store (+ split-K partial offset). mode 1: bf16 store.
// blockIdx.y: bit0 = m-block, >>1 = split-K slice (skA/skB/skC = per-slice elem offsets).
__global__ __launch_bounds__(256, 2) void mfma_gemm(
    const u16* __restrict__ A1, int lda1, int aus1,
    const float* __restrict__ B1, int ldb1, int bus1, int K1,
    const u16* __restrict__ A2, int lda2, int aus2,
    const float* __restrict__ B2, int ldb2, int bus2, int K2,
    void* __restrict__ Cv, int ldc, int cus, int mode,
    int skA, int skB, int skC)
{
    __shared__ __align__(16) u16 As[2][128 * 40];  // rows padded 32->40
    __shared__ __align__(16) u16 Bs[2][128 * 40];  // n-major, k-contiguous
    const int u = blockIdx.z;
    const int n0 = blockIdx.x * 128;
    const int mb = blockIdx.y & 1, sk = blockIdx.y >> 1;
    const int m0 = mb * 128;
    const int tid = threadIdx.x;
    const int ar = tid >> 2, ac = (tid & 3) * 8;
    const int bn = tid & 127, bkg = (tid >> 7) * 16;
    const int w = tid >> 6, lane = tid & 63;
    const int wm = (w >> 1) * 64, wn = (w & 1) * 64;
    const int fr = lane & 31, kh = (lane >> 5) * 8;

    const int ns1 = (K1 + 31) >> 5;
    const int ns2 = K2 ? (K2 + 31) >> 5 : 0;

    const u16* aB1 = A1 + (size_t)sk * skA + (size_t)u * aus1 + (size_t)(m0 + ar) * lda1 + ac;
    const float* bB1 = B1 + (size_t)sk * skB + (size_t)u * bus1 + (size_t)bkg * ldb1 + n0 + bn;
    const u16* aB2 = aB1; const float* bB2 = bB1; int lda2e = lda1, ldb2e = ldb1;
    if (K2) {
        aB2 = A2 + (size_t)u * aus2 + (size_t)(m0 + ar) * lda2 + ac;
        bB2 = B2 + (size_t)u * bus2 + (size_t)bkg * ldb2 + n0 + bn;
        lda2e = lda2; ldb2e = ldb2;
    }

    f32x16 acc[2][2];
    #pragma unroll
    for (int i = 0; i < 2; ++i)
        #pragma unroll
        for (int j = 0; j < 2; ++j)
            #pragma unroll
            for (int r = 0; r < 16; ++r) acc[i][j][r] = 0.f;

    gemm_pipe(aB1, lda1, bB1, ldb1, K1, ns1,
              aB2, lda2e, bB2, ldb2e, K2, ns2,
              ar, ac, bn, bkg, wm, wn, fr, kh,
              As[0], As[1], Bs[0], Bs[1], acc);

    // epilogue. C/D map (verified m74/m101): col=lane&31, row=(reg&3)+8*(reg>>2)+4*(lane>>5)
    const size_t skoff = (size_t)sk * (size_t)skC;
    const int rbase = (lane >> 5) * 4;
    #pragma unroll
    for (int i = 0; i < 2; ++i) {
        #pragma unroll
        for (int j = 0; j < 2; ++j) {
            const int gn = n0 + wn + j * 32 + fr;
            #pragma unroll
            for (int r = 0; r < 16; ++r) {
                const int row = (r & 3) + 8 * (r >> 2) + rbase;
                const int gm = m0 + wm + i * 32 + row;
                const size_t idx = (size_t)u * cus + (size_t)gm * ldc + gn + skoff;
                if (mode == 0) ((float*)Cv)[idx] = acc[i][j][r];
                else           ((u16*)Cv)[idx]  = f2u(acc[i][j][r]);
            }
        }
    }
}

// ---------------- fused kc/qc/vc GEMM: A = ht (M=256,K=512); bx selects weight/output
__global__ __launch_bounds__(256, 2) void mfma_gemm_kqv(
    const u16* __restrict__ ht,
    const float* __restrict__ kc_w, const float* __restrict__ qc_w, const float* __restrict__ vc_w,
    u16* __restrict__ kc, u16* __restrict__ qcb, u16* __restrict__ vc)
{
    __shared__ __align__(16) u16 As[2][128 * 40];
    __shared__ __align__(16) u16 Bs[2][128 * 40];
    const int u = blockIdx.z;
    const int bx = blockIdx.x;
    const int m0 = blockIdx.y * 128;
    const int tid = threadIdx.x;
    const int ar = tid >> 2, ac = (tid & 3) * 8;
    const int bn = tid & 127, bkg = (tid >> 7) * 16;
    const int w = tid >> 6, lane = tid & 63;
    const int wm = (w >> 1) * 64, wn = (w & 1) * 64;
    const int fr = lane & 31, kh = (lane >> 5) * 8;

    const float* Bw; u16* Cd; int ldb, bus, n0, ldc, cus;
    if (bx == 0)      { Bw = kc_w; Cd = kc;  ldb = 128;  bus = 512 * 128;  n0 = 0;              ldc = 3072;  cus = 128;  }
    else if (bx == 1) { Bw = qc_w; Cd = qcb; ldb = 128;  bus = 512 * 128;  n0 = 0;              ldc = 3072;  cus = 128;  }
    else              { Bw = vc_w; Cd = vc;  ldb = 2048; bus = 512 * 2048; n0 = (bx - 2) * 128; ldc = 49152; cus = 2048; }

    const u16* aB = ht + (size_t)u * 512 + (size_t)(m0 + ar) * 12288 + ac;
    const float* bB = Bw + (size_t)u * bus + (size_t)bkg * ldb + n0 + bn;

    f32x16 acc[2][2];
    #pragma unroll
    for (int i = 0; i < 2; ++i)
        #pragma unroll
        for (int j = 0; j < 2; ++j)
            #pragma unroll
            for (int r = 0; r < 16; ++r) acc[i][j][r] = 0.f;

    gemm_pipe(aB, 12288, bB, ldb, 512, 16,
              aB, 12288, bB, ldb, 0, 0,
              ar, ac, bn, bkg, wm, wn, fr, kh,
              As[0], As[1], Bs[0], Bs[1], acc);

    const int rbase = (lane >> 5) * 4;
    #pragma unroll
    for (int i = 0; i < 2; ++i) {
        #pragma unroll
        for (int j = 0; j < 2; ++j) {
            const int gn = n0 + wn + j * 32 + fr;
            #pragma unroll
            for (int r = 0; r < 16; ++r) {
                const int row = (r & 3) + 8 * (r >> 2) + rbase;
                const int gm = m0 + wm + i * 32 + row;
                Cd[(size_t)u * cus + (size_t)gm * ldc + gn] = f2u(acc[i][j][r]);
            }
        }
    }
}

// ---------------- Stage 6: LSTM gates; writes h_t (ws, bf16) and cs_new (d_out, f32 select)
__global__ __launch_bounds__(256) void gates_kernel(
    const float* __restrict__ preact, const float* __restrict__ cs,
    const float* __restrict__ mask,
    u16* __restrict__ ht, float* __restrict__ out_cs)
{
    const int idx = blockIdx.x * 256 + threadIdx.x;  // exactly B*U*512
    const int h = idx & 511, bu = idx >> 9;
    const float* pre = preact + (size_t)bu * 2048;
    const float it = 1.f / (1.f + expf(-pre[h]));
    const float ft = 1.f / (1.f + expf(-pre[512 + h]));
    const float ot = 1.f / (1.f + expf(-pre[1024 + h]));
    const float gt = tanhf(pre[1536 + h]);
    const float c = cs[idx] * ft + it * gt;
    ht[idx] = f2u(ot * tanhf(c));
    out_cs[idx] = (mask[bu] != 0.f) ? c : cs[idx];  // passthrough bit-exact when unmasked
}

// ---------------- Stage 10: attention, one block per (u,b), wave per head
__global__ __launch_bounds__(256) void attn_kernel(
    const u16* __restrict__ qc, const u16* __restrict__ kc, const u16* __restrict__ vc,
    const float* __restrict__ mask, u16* __restrict__ ctx)
{
    const int u = blockIdx.x, b = blockIdx.y;
    if (mask[b * 24 + u] == 0.f) return;  // ctx rows discarded by co epilogue
    const int nc = threadIdx.x >> 6, lane = threadIdx.x & 63;
    __shared__ float kcs[4][24][32];
    __shared__ float qv[4][32];
    __shared__ float ss[4][24];
    __shared__ float ps[4][24];
    for (int i = lane; i < 24 * 32; i += 64) {
        const int t = i >> 5, k = i & 31;
        kcs[nc][t][k] = u2f(kc[((size_t)(b * 24 + t)) * 128 + nc * 32 + k]);
    }
    if (lane < 32) qv[nc][lane] = u2f(qc[((size_t)(b * 24 + u)) * 128 + nc * 32 + lane]);
    __syncthreads();
    if (lane < 24) {
        float s = 0.f;
        for (int k = 0; k < 32; ++k) s += qv[nc][k] * kcs[nc][lane][k];
        ss[nc][lane] = s * 0.17677669529663687f;  // 1/sqrt(32)
    }
    __syncthreads();
    float m = -1e30f;
    for (int t = 0; t < 24; ++t) m = fmaxf(m, ss[nc][t]);
    float sum = 0.f;
    for (int t = 0; t < 24; ++t) sum += expf(ss[nc][t] - m);
    const float inv = 1.f / sum;
    if (lane < 24) ps[nc][lane] = expf(ss[nc][lane] - m) * inv;
    __syncthreads();
    float acc[8] = {};
    const u16* vcb = vc + (size_t)b * 24 * 2048 + nc * 512 + lane;
    for (int t = 0; t < 24; ++t) {
        const float pt = ps[nc][t];
        const u16* vr = vcb + (size_t)t * 2048;
        #pragma unroll
        for (int j = 0; j < 8; ++j) acc[j] += pt * u2f(vr[j * 64]);
    }
    u16* cb = ctx + ((size_t)(b * 24 + u)) * 2048 + nc * 512 + lane;
    #pragma unroll
    for (int j = 0; j < 8; ++j) cb[j * 64] = f2u(acc[j]);
}

// ---------------- co split-K reduce + epilogue: hs_new = mask ? p0+p1+h_t : hs
__global__ __launch_bounds__(256) void co_reduce(
    const float* __restrict__ p, const float* __restrict__ mask,
    const u16* __restrict__ ht, const float* __restrict__ hs,
    float* __restrict__ out_hs)
{
    const int idx = blockIdx.x * 256 + threadIdx.x;  // exactly B*U*512
    const int bu = idx >> 9;
    out_hs[idx] = (mask[bu] != 0.f)
        ? (p[idx] + p[idx + 6144 * 512] + u2f(ht[idx]))
        : hs[idx];
}

extern "C" void kernel_launch(void* const* d_in, const int* in_sizes, int n_in,
                              void* d_out, int out_size, void* d_ws, size_t ws_size,
                              hipStream_t stream)
{
    (void)in_sizes; (void)n_in; (void)out_size; (void)ws_size;
    const float* x       = (const float*)d_in[0];
    const float* hs      = (const float*)d_in[1];
    const float* cs      = (const float*)d_in[2];
    const float* key_w   = (const float*)d_in[3];
    const float* key_b   = (const float*)d_in[4];
    const float* value_w = (const float*)d_in[5];
    const float* value_b = (const float*)d_in[6];
    const float* query_w = (const float*)d_in[7];
    const float* i2h_w   = (const float*)d_in[8];
    const float* h2h_w   = (const float*)d_in[9];
    const float* qc_w    = (const float*)d_in[10];
    const float* kc_w    = (const float*)d_in[11];
    const float* vc_w    = (const float*)d_in[12];
    const float* co_w    = (const float*)d_in[13];

    // ws layout (bytes); vc/ctx alias the dead preact region; co partials alias dead vc
    char* ws = (char*)d_ws;
    float* k0     = (float*)(ws + 0);          // 256*64*4    = 65536
    float* v0     = (float*)(ws + 65536);      // 256*400*4   = 409600
    float* scores = (float*)(ws + 475136);     // 256*24*2*4  = 49152
    float* probs  = (float*)(ws + 524288);     // 49152
    float* mask   = (float*)(ws + 573440);     // 256*24*4    = 24576
    u16*   inp    = (u16*)  (ws + 598016);     // 256*24*416*2 = 5111808 (K padded to 416)
    float* preact = (float*)(ws + 5709824);    // 256*24*2048*4 = 50331648
    u16*   vc     = (u16*)  (ws + 5709824);    // alias (preact dead after gates)
    float* co_p   = (float*)(ws + 5709824);    // alias (vc dead after attn); 2*6144*512*4 = 25165824
    u16*   ctx    = (u16*)  (ws + 30875648);   // alias, second half of preact region
    u16*   ht     = (u16*)  (ws + 56041472);   // 256*24*512*2 = 6291456
    u16*   kc     = (u16*)  (ws + 62332928);   // 256*24*128*2 = 1572864
    u16*   qcb    = (u16*)  (ws + 63905792);   // 1572864
    u16*   hsb    = (u16*)  (ws + 65478656);   // 6291456 (total ~71.8MB)

    float* out_hs = (float*)d_out;
    float* out_cs = out_hs + (size_t)256 * 24 * 512;

    kv_kernel<<<256, 512, 0, stream>>>(x, key_w, key_b, value_w, value_b, k0, v0);
    qscore_kernel<<<dim3(24, 256), 64, 0, stream>>>(hs, query_w, k0, key_b, scores, hsb);
    topk_kernel<<<256, 64, 0, stream>>>(scores, mask, probs);
    inp_kernel<<<(256 * 24 * 416) / 256, 256, 0, stream>>>(probs, v0, value_b, mask, inp);

    // preact = inp@i2h_w[u] + hs@h2h_w[u]   (M=256, N=2048, K=400+512)
    mfma_gemm<<<dim3(16, 2, 24), 256, 0, stream>>>(
        inp, 9984, 416, i2h_w, 2048, 400 * 2048, 400,
        hsb, 12288, 512, h2h_w, 2048, 512 * 2048, 512,
        preact, 49152, 2048, 0, 0, 0, 0);

    gates_kernel<<<12288, 256, 0, stream>>>(preact, cs, mask, ht, out_cs);

    // kc/qc/vc fused: M=256, K=512; N = 128 + 128 + 2048 (18 n-blocks)
    mfma_gemm_kqv<<<dim3(18, 2, 24), 256, 0, stream>>>(ht, kc_w, qc_w, vc_w, kc, qcb, vc);

    attn_kernel<<<dim3(24, 256), 256, 0, stream>>>(qcb, kc, vc, mask, ctx);

    // co partials: M=256, N=512, K=2048 split into 2x1024 (grid.y = 2 m-blocks x 2 k-slices)
    mfma_gemm<<<dim3(4, 4, 24), 256, 0, stream>>>(
        ctx, 49152, 2048, co_w, 512, 2048 * 512, 1024,
        nullptr, 0, 0, nullptr, 0, 0, 0,
        co_p, 12288, 512, 0, 1024, 1024 * 512, 6144 * 512);

    co_reduce<<<12288, 256, 0, stream>>>(co_p, mask, ht, hs, out_hs);
}